// Round 17
// baseline (167.792 us; speedup 1.0000x reference)
//
#include <hip/hip_runtime.h>

#define NN 2048
#define EE 768
#define HH 12
#define DD 64
#define BHX 48
#define MM 8192

typedef unsigned short u16;
typedef unsigned int u32;
typedef __attribute__((ext_vector_type(8))) short bf16x8;
typedef __attribute__((ext_vector_type(4))) float f32x4;

#if __has_builtin(__builtin_amdgcn_exp2f)
#define EX2(x) __builtin_amdgcn_exp2f(x)
#else
#define EX2(x) exp2f(x)
#endif

#define MFMA16(a, b, c) __builtin_amdgcn_mfma_f32_16x16x32_bf16((a), (b), (c), 0, 0, 0)

__device__ __forceinline__ u16 f2bf(float f) {
    u32 u = __builtin_bit_cast(u32, f);
    u32 r = (u + 0x7FFFu + ((u >> 16) & 1u)) >> 16;
    return (u16)r;
}
__device__ __forceinline__ float bf2f(u16 b) {
    u32 u = ((u32)b) << 16;
    return __builtin_bit_cast(float, u);
}
// Round-to-nearest bf16 pair pack, pure C (no asm — cvtpk stays BANNED per r2/r9).
__device__ __forceinline__ u32 pack_rn(float a, float b) {
    u32 ua = __builtin_bit_cast(u32, a) + 0x8000u;
    u32 ub = __builtin_bit_cast(u32, b) + 0x8000u;
    return (ub & 0xFFFF0000u) | (ua >> 16);
}
__device__ __forceinline__ void gload_lds16(const u16* g, u16* l) {
    __builtin_amdgcn_global_load_lds((const __attribute__((address_space(1))) void*)g,
                                     (__attribute__((address_space(3))) void*)l, 16, 0, 0);
}

// ---------------- prep: x fp32 -> bf16 ---------------- (proven)
__global__ __launch_bounds__(256) void k_cvt_x(const float* __restrict__ x, u16* __restrict__ xb, int n8) {
    int i = blockIdx.x * 256 + threadIdx.x;
    if (i >= n8) return;
    const float4* x4 = (const float4*)x;
    float4 a = x4[i * 2], b = x4[i * 2 + 1];
    uint4 o;
    o.x = (u32)f2bf(a.x) | ((u32)f2bf(a.y) << 16);
    o.y = (u32)f2bf(a.z) | ((u32)f2bf(a.w) << 16);
    o.z = (u32)f2bf(b.x) | ((u32)f2bf(b.y) << 16);
    o.w = (u32)f2bf(b.z) | ((u32)f2bf(b.w) << 16);
    ((uint4*)xb)[i] = o;
}

// ---------------- prep: W -> W^T bf16, coalesced LDS transpose ---------------- (round-10 proven)
__global__ __launch_bounds__(256) void k_wt(const float* __restrict__ Wq, const float* __restrict__ Wk,
                                            const float* __restrict__ Wv, u16* __restrict__ wt) {
    __shared__ u16 lt[64 * 80];
    const int z = blockIdx.z;
    const float* W = (z == 0) ? Wq : (z == 1 ? Wk : Wv);
    const int k0 = blockIdx.x * 64, j0 = blockIdx.y * 64;
    const int tid = threadIdx.x;
#pragma unroll
    for (int p = 0; p < 4; ++p) {
        int c = p * 256 + tid;
        int kk = c >> 4, j4 = (c & 15) * 4;
        float4 v = *(const float4*)(W + (size_t)(k0 + kk) * EE + j0 + j4);
        lt[(j4 + 0) * 80 + kk] = f2bf(v.x);
        lt[(j4 + 1) * 80 + kk] = f2bf(v.y);
        lt[(j4 + 2) * 80 + kk] = f2bf(v.z);
        lt[(j4 + 3) * 80 + kk] = f2bf(v.w);
    }
    __syncthreads();
    u16* dstz = wt + (size_t)z * EE * EE;
#pragma unroll
    for (int p = 0; p < 2; ++p) {
        int c = p * 256 + tid;
        int j = c >> 3, kc = c & 7;
        uint4 o = *(const uint4*)&lt[j * 80 + kc * 8];
        *(uint4*)(dstz + (size_t)(j0 + j) * EE + k0 + kc * 8) = o;
    }
}

// ---------------- QKV projection GEMM: double-buffered, 1 barrier/K-step (THE ONE CHANGE) ----------------
// r1's single-buffered loop had TWO vmcnt(0)-drain barriers per K-step (48/block); this is the
// k_attn-proven dbuf prefetch structure: STAGE(next) -> compute(cur) -> one barrier. 24 drains.
// Runtime niter + unroll(disable) prevents full-unroll VGPR blowup (r14 lesson). LDS 32 KB.
__global__ __launch_bounds__(256) void k_proj(const u16* __restrict__ xb, const u16* __restrict__ wt,
                                              const float* __restrict__ bq, const float* __restrict__ bk,
                                              const float* __restrict__ bv, u16* __restrict__ qh,
                                              u16* __restrict__ kh, u16* __restrict__ vh, int niter) {
    __shared__ u16 lA[2][128 * 32];
    __shared__ u16 lB[2][128 * 32];
    const int z = blockIdx.z;
    const u16* Wz = wt + (size_t)z * EE * EE;
    const float* bias = (z == 0) ? bq : (z == 1 ? bk : bv);
    u16* outp = (z == 0) ? qh : (z == 1 ? kh : vh);
    const float oscale = (z == 0) ? (0.28867513459481287f * 1.4426950408889634f) : 1.0f;
    const int tid = threadIdx.x;
    const int lane = tid & 63, w = tid >> 6;
    const int wr = w >> 1, wc = w & 1, lr = lane & 15, lg = lane >> 4;
    const int m0 = blockIdx.x * 128, n0 = blockIdx.y * 128;

    // staging source pointers (r1-proven formulas, hoisted): c = i*256+tid, row=c>>2, cc=c&3
    const u16* ap[2];
    const u16* bp[2];
#pragma unroll
    for (int i = 0; i < 2; i++) {
        int c = i * 256 + tid;
        int row = c >> 2, cc = c & 3;
        ap[i] = xb + (size_t)(m0 + row) * EE + cc * 8;
        bp[i] = Wz + (size_t)(n0 + row) * EE + cc * 8;
    }

#define STAGE_AB(buf, kt)                                               \
    do {                                                                \
        _Pragma("unroll") for (int i = 0; i < 2; i++) {                 \
            int c = i * 256 + tid;                                      \
            gload_lds16(ap[i] + (kt), &lA[buf][c * 8]);                 \
            gload_lds16(bp[i] + (kt), &lB[buf][c * 8]);                 \
        }                                                               \
    } while (0)

    f32x4 acc[4][4];
#pragma unroll
    for (int mi = 0; mi < 4; mi++)
#pragma unroll
        for (int ni = 0; ni < 4; ni++) acc[mi][ni] = (f32x4){0.f, 0.f, 0.f, 0.f};

    STAGE_AB(0, 0);
    __syncthreads();
    int cur = 0;
#pragma clang loop unroll(disable)
    for (int it = 0; it < niter; ++it) {
        if (it < niter - 1) STAGE_AB(cur ^ 1, (it + 1) * 32);
        bf16x8 af[4], bfr[4];
#pragma unroll
        for (int mi = 0; mi < 4; mi++) af[mi] = *(const bf16x8*)&lA[cur][(wr * 64 + mi * 16 + lr) * 32 + lg * 8];
#pragma unroll
        for (int ni = 0; ni < 4; ni++) bfr[ni] = *(const bf16x8*)&lB[cur][(wc * 64 + ni * 16 + lr) * 32 + lg * 8];
#pragma unroll
        for (int mi = 0; mi < 4; mi++)
#pragma unroll
            for (int ni = 0; ni < 4; ni++) acc[mi][ni] = MFMA16(af[mi], bfr[ni], acc[mi][ni]);
        __syncthreads();
        cur ^= 1;
    }
#undef STAGE_AB

#pragma unroll
    for (int ni = 0; ni < 4; ni++) {
        int col = n0 + wc * 64 + ni * 16 + lr;
        float bb = bias[col];
        int h = col >> 6, dd = col & 63;
#pragma unroll
        for (int mi = 0; mi < 4; mi++) {
            int rowbase = m0 + wr * 64 + mi * 16 + lg * 4;
#pragma unroll
            for (int r = 0; r < 4; r++) {
                int row = rowbase + r;
                int b = row >> 11, nn = row & 2047;
                outp[(((size_t)b * HH + h) * NN + nn) * DD + dd] = f2bf((acc[mi][ni][r] + bb) * oscale);
            }
        }
    }
}

// ---------------- column stats: 32 k-cols/wave, q-split x2, runtime trip count ---------------- (r16 proven)
__global__ __launch_bounds__(512) void k_stats(const u16* __restrict__ qh, const u16* __restrict__ kh,
                                               float* __restrict__ lsum, int niter) {
    __shared__ u16 lds[2][4096];
    const int lin = blockIdx.x;
    const int nb = (lin & 7) * 96 + (lin >> 3);
    const int qs = nb & 1, kb = (nb >> 1) & 7, bh = nb >> 4;
    const int tid = threadIdx.x, lane = tid & 63, w = tid >> 6;
    const int lr = lane & 15, lg = lane >> 4;
    const int kw0 = kb * 256 + w * 32;
    const u16* Q = qh + (size_t)bh * NN * DD + (size_t)(qs * 1024) * DD;
    const u16* K = kh + (size_t)bh * NN * DD;

    bf16x8 kf[2][2];
#pragma unroll
    for (int t = 0; t < 2; t++)
#pragma unroll
        for (int kk = 0; kk < 2; kk++)
            kf[t][kk] = *(const bf16x8*)(K + (size_t)(kw0 + t * 16 + lr) * DD + kk * 32 + lg * 8);

    const int c = tid;
    const int f = c >> 6;
    const int qrow = (f >> 1) * 16 + (c & 15);
    const int doff = (f & 1) * 32 + ((c >> 4) & 3) * 8;
    const u16* qp = Q + (size_t)qrow * DD + doff;

#define STAGE_Q(buf, q0) gload_lds16(qp + (size_t)(q0) * DD, &lds[buf][c * 8])

    STAGE_Q(0, 0);
    __syncthreads();
    float lacc[2] = {0.f, 0.f};
    int cur = 0;
#pragma clang loop unroll(disable)
    for (int it = 0; it < niter; ++it) {
        if (it < niter - 1) STAGE_Q(cur ^ 1, (it + 1) * 64);
#pragma unroll
        for (int qt = 0; qt < 4; ++qt) {
            bf16x8 qa0 = *(const bf16x8*)&lds[cur][(qt * 2 + 0) * 512 + lane * 8];
            bf16x8 qa1 = *(const bf16x8*)&lds[cur][(qt * 2 + 1) * 512 + lane * 8];
#pragma unroll
            for (int t = 0; t < 2; t++) {
                f32x4 ss = (f32x4){0.f, 0.f, 0.f, 0.f};
                ss = MFMA16(qa0, kf[t][0], ss);
                ss = MFMA16(qa1, kf[t][1], ss);
                lacc[t] += EX2(ss[0]) + EX2(ss[1]) + EX2(ss[2]) + EX2(ss[3]);
            }
        }
        __syncthreads();
        cur ^= 1;
    }
#undef STAGE_Q
#pragma unroll
    for (int t = 0; t < 2; t++) {
        float v = lacc[t];
        v += __shfl_xor(v, 16);
        v += __shfl_xor(v, 32);
        if (lane < 16)
            lsum[(size_t)qs * BHX * NN + (size_t)bh * NN + kw0 + t * 16 + lane] = v;
    }
}

// ---------------- V transpose + fold 1/(l0+l1), k-PERMUTED ---------------- (r14/r15-proven combine)
__global__ __launch_bounds__(256) void k_vtrans(const u16* __restrict__ vh, const float* __restrict__ lsum,
                                                u16* __restrict__ vt) {
    __shared__ u16 lds[64 * 80];
    const int bh = blockIdx.x, n0 = blockIdx.y * 64;
    const int tid = threadIdx.x;
    const u16* src = vh + (size_t)bh * NN * DD + (size_t)n0 * DD;
    const float* l0 = lsum + (size_t)bh * NN + n0;
    const float* l1 = lsum + (size_t)BHX * NN + (size_t)bh * NN + n0;
#pragma unroll
    for (int i = 0; i < 2; i++) {
        int c = i * 256 + tid;
        int row = c >> 3, dc = c & 7;
        uint4 vraw = *(const uint4*)(src + row * DD + dc * 8);
        float rk = 1.0f / (l0[row] + l1[row]);
        u32 uu[4] = {vraw.x, vraw.y, vraw.z, vraw.w};
#pragma unroll
        for (int j = 0; j < 4; j++) {
            u16 e0 = (u16)(uu[j] & 0xffff), e1 = (u16)(uu[j] >> 16);
            lds[(dc * 8 + 2 * j) * 80 + row] = f2bf(rk * bf2f(e0));
            lds[(dc * 8 + 2 * j + 1) * 80 + row] = f2bf(rk * bf2f(e1));
        }
    }
    __syncthreads();
    u16* dst = vt + (size_t)bh * DD * NN + n0;
#pragma unroll
    for (int i = 0; i < 2; i++) {
        int c = i * 256 + tid;
        int d = c >> 3, nc = c & 7;
        int w0 = nc * 8;
        uint2 a = *(const uint2*)&lds[d * 80 + w0];
        uint2 b = *(const uint2*)&lds[d * 80 + w0 + 4];
        int hi32 = (w0 >> 5) * 32;
        int wa = w0 & 31, wb = (w0 + 4) & 31;
        int ca = ((wa & 15) >> 2) * 8 + (wa >> 4) * 4;
        int cb = ((wb & 15) >> 2) * 8 + (wb >> 4) * 4;
        *(uint2*)(dst + (size_t)d * NN + hi32 + ca) = a;
        *(uint2*)(dst + (size_t)d * NN + hi32 + cb) = b;
    }
}

// ---------------- output pass: 8 waves x 16q, grid 768, pack_rn ---------------- (round-13 proven)
__global__ __launch_bounds__(512) void k_attn(const u16* __restrict__ qh, const u16* __restrict__ kh,
                                              const u16* __restrict__ vt, float* __restrict__ out) {
    __shared__ u16 lds[2][8192];  // per buf: K 8 regions x 512 | V 8 regions x 512
    const int lin = blockIdx.x;
    const int nb = (lin & 7) * 96 + (lin >> 3); // bijective XCD swizzle
    const int bh = nb >> 4, qb = nb & 15;
    const int tid = threadIdx.x, lane = tid & 63, w = tid >> 6;  // w in [0,8)
    const int lr = lane & 15, lg = lane >> 4;
    const int qw0 = qb * 128 + w * 16;  // 16 q-rows per wave
    const u16* Q = qh + (size_t)bh * NN * DD;
    const u16* K = kh + (size_t)bh * NN * DD;
    const u16* V = vt + (size_t)bh * DD * NN;

    bf16x8 qf[2];
#pragma unroll
    for (int kk = 0; kk < 2; kk++)
        qf[kk] = *(const bf16x8*)(Q + (size_t)(qw0 + lr) * DD + kk * 32 + lg * 8);

    const int c = tid;
    const int f = c >> 6;
    const int rk = (f >> 2) * 32 + ((f >> 1) & 1) * 16 + (c & 15);
    const int doff = (f & 1) * 32 + ((c >> 4) & 3) * 8;
    const u16* kp = K + (size_t)rk * DD + doff;
    const int drow = (f & 3) * 16 + (c & 15);
    const int koff = (f >> 2) * 32 + ((c >> 4) & 3) * 8;
    const u16* vp = V + (size_t)drow * NN + koff;

#define STAGE_KV(buf, k0)                                          \
    do {                                                           \
        gload_lds16(kp + (size_t)(k0) * DD, &lds[buf][c * 8]);     \
        gload_lds16(vp + (size_t)(k0), &lds[buf][4096 + c * 8]);   \
    } while (0)

    f32x4 acc[4];
#pragma unroll
    for (int di = 0; di < 4; di++) acc[di] = (f32x4){0.f, 0.f, 0.f, 0.f};

    STAGE_KV(0, 0);
    __syncthreads();
    int cur = 0;
    for (int it = 0; it < 32; ++it) {
        if (it < 31) STAGE_KV(cur ^ 1, (it + 1) * 64);
        const u16* Lk = &lds[cur][0];
        const u16* Lv = &lds[cur][4096];
#pragma unroll
        for (int kc = 0; kc < 2; ++kc) {
            bf16x8 kf2[2][2];
#pragma unroll
            for (int t = 0; t < 2; t++)
#pragma unroll
                for (int kk = 0; kk < 2; kk++)
                    kf2[t][kk] = *(const bf16x8*)&Lk[((kc * 2 + t) * 2 + kk) * 512 + lane * 8];
            bf16x8 vf[4];
#pragma unroll
            for (int di = 0; di < 4; di++)
                vf[di] = *(const bf16x8*)&Lv[(kc * 4 + di) * 512 + lane * 8];
            f32x4 s0 = (f32x4){0.f, 0.f, 0.f, 0.f}, s1 = (f32x4){0.f, 0.f, 0.f, 0.f};
            s0 = MFMA16(kf2[0][0], qf[0], s0);
            s0 = MFMA16(kf2[0][1], qf[1], s0);
            s1 = MFMA16(kf2[1][0], qf[0], s1);
            s1 = MFMA16(kf2[1][1], qf[1], s1);
            uint4 pu;
            pu.x = pack_rn(EX2(s0[0]), EX2(s0[1]));
            pu.y = pack_rn(EX2(s0[2]), EX2(s0[3]));
            pu.z = pack_rn(EX2(s1[0]), EX2(s1[1]));
            pu.w = pack_rn(EX2(s1[2]), EX2(s1[3]));
            bf16x8 pa = __builtin_bit_cast(bf16x8, pu);
#pragma unroll
            for (int di = 0; di < 4; di++) acc[di] = MFMA16(pa, vf[di], acc[di]);
        }
        __syncthreads();
        cur ^= 1;
    }
#undef STAGE_KV

    const int b = bh / HH, h = bh % HH;
#pragma unroll
    for (int di = 0; di < 4; di++)
#pragma unroll
        for (int r = 0; r < 4; r++) {
            int q = qw0 + lg * 4 + r;
            int d = di * 16 + lr;
            out[((size_t)(b * NN + q)) * EE + h * DD + d] = acc[di][r];
        }
}

extern "C" void kernel_launch(void* const* d_in, const int* in_sizes, int n_in,
                              void* d_out, int out_size, void* d_ws, size_t ws_size,
                              hipStream_t stream) {
    const float* x = (const float*)d_in[0];
    const float* Wq = (const float*)d_in[1];
    const float* bq = (const float*)d_in[2];
    const float* Wk = (const float*)d_in[3];
    const float* bk = (const float*)d_in[4];
    const float* Wv = (const float*)d_in[5];
    const float* bv = (const float*)d_in[6];
    float* out = (float*)d_out;
    char* ws = (char*)d_ws;

    size_t off = 0;
    u16* xb = (u16*)(ws + off); off += (size_t)MM * EE * 2;
    u16* wt = (u16*)(ws + off); off += (size_t)3 * EE * EE * 2;
    u16* qh = (u16*)(ws + off); off += (size_t)BHX * NN * DD * 2;
    u16* kh = (u16*)(ws + off); off += (size_t)BHX * NN * DD * 2;
    u16* vh = (u16*)(ws + off); off += (size_t)BHX * NN * DD * 2;
    u16* vt = (u16*)(ws + off); off += (size_t)BHX * NN * DD * 2;
    float* lsum = (float*)(ws + off); off += (size_t)2 * BHX * NN * 4;  // two q-half partials

    k_cvt_x<<<dim3(3072), dim3(256), 0, stream>>>(x, xb, MM * EE / 8);
    k_wt<<<dim3(12, 12, 3), dim3(256), 0, stream>>>(Wq, Wk, Wv, wt);
    k_proj<<<dim3(64, 6, 3), dim3(256), 0, stream>>>(xb, wt, bq, bk, bv, qh, kh, vh, 24);
    k_stats<<<dim3(768), dim3(512), 0, stream>>>(qh, kh, lsum, 16);
    k_vtrans<<<dim3(48, 32), dim3(256), 0, stream>>>(vh, lsum, vt);
    k_attn<<<dim3(768), dim3(512), 0, stream>>>(qh, kh, vt, out);
}

// Round 18
// 164.645 us; speedup vs baseline: 1.0191x; 1.0191x over previous
//
#include <hip/hip_runtime.h>

#define NN 2048
#define EE 768
#define HH 12
#define DD 64
#define BHX 48
#define MM 8192

typedef unsigned short u16;
typedef unsigned int u32;
typedef __attribute__((ext_vector_type(8))) short bf16x8;
typedef __attribute__((ext_vector_type(4))) float f32x4;

#if __has_builtin(__builtin_amdgcn_exp2f)
#define EX2(x) __builtin_amdgcn_exp2f(x)
#else
#define EX2(x) exp2f(x)
#endif

#define MFMA16(a, b, c) __builtin_amdgcn_mfma_f32_16x16x32_bf16((a), (b), (c), 0, 0, 0)

__device__ __forceinline__ u16 f2bf(float f) {
    u32 u = __builtin_bit_cast(u32, f);
    u32 r = (u + 0x7FFFu + ((u >> 16) & 1u)) >> 16;
    return (u16)r;
}
__device__ __forceinline__ float bf2f(u16 b) {
    u32 u = ((u32)b) << 16;
    return __builtin_bit_cast(float, u);
}
// Round-to-nearest bf16 pair pack, pure C (no asm — cvtpk stays BANNED per r2/r9).
__device__ __forceinline__ u32 pack_rn(float a, float b) {
    u32 ua = __builtin_bit_cast(u32, a) + 0x8000u;
    u32 ub = __builtin_bit_cast(u32, b) + 0x8000u;
    return (ub & 0xFFFF0000u) | (ua >> 16);
}
__device__ __forceinline__ void gload_lds16(const u16* g, u16* l) {
    __builtin_amdgcn_global_load_lds((const __attribute__((address_space(1))) void*)g,
                                     (__attribute__((address_space(3))) void*)l, 16, 0, 0);
}

// ---------------- prep: x fp32 -> bf16 ---------------- (proven)
__global__ __launch_bounds__(256) void k_cvt_x(const float* __restrict__ x, u16* __restrict__ xb, int n8) {
    int i = blockIdx.x * 256 + threadIdx.x;
    if (i >= n8) return;
    const float4* x4 = (const float4*)x;
    float4 a = x4[i * 2], b = x4[i * 2 + 1];
    uint4 o;
    o.x = (u32)f2bf(a.x) | ((u32)f2bf(a.y) << 16);
    o.y = (u32)f2bf(a.z) | ((u32)f2bf(a.w) << 16);
    o.z = (u32)f2bf(b.x) | ((u32)f2bf(b.y) << 16);
    o.w = (u32)f2bf(b.z) | ((u32)f2bf(b.w) << 16);
    ((uint4*)xb)[i] = o;
}

// ---------------- prep: W -> W^T bf16, coalesced LDS transpose ---------------- (round-10 proven)
__global__ __launch_bounds__(256) void k_wt(const float* __restrict__ Wq, const float* __restrict__ Wk,
                                            const float* __restrict__ Wv, u16* __restrict__ wt) {
    __shared__ u16 lt[64 * 80];
    const int z = blockIdx.z;
    const float* W = (z == 0) ? Wq : (z == 1 ? Wk : Wv);
    const int k0 = blockIdx.x * 64, j0 = blockIdx.y * 64;
    const int tid = threadIdx.x;
#pragma unroll
    for (int p = 0; p < 4; ++p) {
        int c = p * 256 + tid;
        int kk = c >> 4, j4 = (c & 15) * 4;
        float4 v = *(const float4*)(W + (size_t)(k0 + kk) * EE + j0 + j4);
        lt[(j4 + 0) * 80 + kk] = f2bf(v.x);
        lt[(j4 + 1) * 80 + kk] = f2bf(v.y);
        lt[(j4 + 2) * 80 + kk] = f2bf(v.z);
        lt[(j4 + 3) * 80 + kk] = f2bf(v.w);
    }
    __syncthreads();
    u16* dstz = wt + (size_t)z * EE * EE;
#pragma unroll
    for (int p = 0; p < 2; ++p) {
        int c = p * 256 + tid;
        int j = c >> 3, kc = c & 7;
        uint4 o = *(const uint4*)&lt[j * 80 + kc * 8];
        *(uint4*)(dstz + (size_t)(j0 + j) * EE + k0 + kc * 8) = o;
    }
}

// ---------------- QKV projection GEMM ---------------- (r16-proven single-buffered form, reverted)
__global__ __launch_bounds__(256) void k_proj(const u16* __restrict__ xb, const u16* __restrict__ wt,
                                              const float* __restrict__ bq, const float* __restrict__ bk,
                                              const float* __restrict__ bv, u16* __restrict__ qh,
                                              u16* __restrict__ kh, u16* __restrict__ vh) {
    __shared__ u16 lA[128 * 32];
    __shared__ u16 lB[128 * 32];
    const int z = blockIdx.z;
    const u16* Wz = wt + (size_t)z * EE * EE;
    const float* bias = (z == 0) ? bq : (z == 1 ? bk : bv);
    u16* outp = (z == 0) ? qh : (z == 1 ? kh : vh);
    const float oscale = (z == 0) ? (0.28867513459481287f * 1.4426950408889634f) : 1.0f;
    const int tid = threadIdx.x;
    const int lane = tid & 63, w = tid >> 6;
    const int wr = w >> 1, wc = w & 1, lr = lane & 15, lg = lane >> 4;
    const int m0 = blockIdx.x * 128, n0 = blockIdx.y * 128;

    f32x4 acc[4][4];
#pragma unroll
    for (int mi = 0; mi < 4; mi++)
#pragma unroll
        for (int ni = 0; ni < 4; ni++) acc[mi][ni] = (f32x4){0.f, 0.f, 0.f, 0.f};

    for (int kt = 0; kt < EE; kt += 32) {
#pragma unroll
        for (int i = 0; i < 2; i++) {
            int c = i * 256 + tid;
            int row = c >> 2, cc = c & 3;
            gload_lds16(xb + (size_t)(m0 + row) * EE + kt + cc * 8, &lA[c * 8]);
            gload_lds16(Wz + (size_t)(n0 + row) * EE + kt + cc * 8, &lB[c * 8]);
        }
        __syncthreads();
        bf16x8 af[4], bfr[4];
#pragma unroll
        for (int mi = 0; mi < 4; mi++) af[mi] = *(const bf16x8*)&lA[(wr * 64 + mi * 16 + lr) * 32 + lg * 8];
#pragma unroll
        for (int ni = 0; ni < 4; ni++) bfr[ni] = *(const bf16x8*)&lB[(wc * 64 + ni * 16 + lr) * 32 + lg * 8];
#pragma unroll
        for (int mi = 0; mi < 4; mi++)
#pragma unroll
            for (int ni = 0; ni < 4; ni++) acc[mi][ni] = MFMA16(af[mi], bfr[ni], acc[mi][ni]);
        __syncthreads();
    }

#pragma unroll
    for (int ni = 0; ni < 4; ni++) {
        int col = n0 + wc * 64 + ni * 16 + lr;
        float bb = bias[col];
        int h = col >> 6, dd = col & 63;
#pragma unroll
        for (int mi = 0; mi < 4; mi++) {
            int rowbase = m0 + wr * 64 + mi * 16 + lg * 4;
#pragma unroll
            for (int r = 0; r < 4; r++) {
                int row = rowbase + r;
                int b = row >> 11, nn = row & 2047;
                outp[(((size_t)b * HH + h) * NN + nn) * DD + dd] = f2bf((acc[mi][ni][r] + bb) * oscale);
            }
        }
    }
}

// ---------------- column stats: 32 k-cols/wave, q-split x2, runtime trip count ---------------- (r16 proven)
__global__ __launch_bounds__(512) void k_stats(const u16* __restrict__ qh, const u16* __restrict__ kh,
                                               float* __restrict__ lsum, int niter) {
    __shared__ u16 lds[2][4096];
    const int lin = blockIdx.x;
    const int nb = (lin & 7) * 96 + (lin >> 3);
    const int qs = nb & 1, kb = (nb >> 1) & 7, bh = nb >> 4;
    const int tid = threadIdx.x, lane = tid & 63, w = tid >> 6;
    const int lr = lane & 15, lg = lane >> 4;
    const int kw0 = kb * 256 + w * 32;
    const u16* Q = qh + (size_t)bh * NN * DD + (size_t)(qs * 1024) * DD;
    const u16* K = kh + (size_t)bh * NN * DD;

    bf16x8 kf[2][2];
#pragma unroll
    for (int t = 0; t < 2; t++)
#pragma unroll
        for (int kk = 0; kk < 2; kk++)
            kf[t][kk] = *(const bf16x8*)(K + (size_t)(kw0 + t * 16 + lr) * DD + kk * 32 + lg * 8);

    const int c = tid;
    const int f = c >> 6;
    const int qrow = (f >> 1) * 16 + (c & 15);
    const int doff = (f & 1) * 32 + ((c >> 4) & 3) * 8;
    const u16* qp = Q + (size_t)qrow * DD + doff;

#define STAGE_Q(buf, q0) gload_lds16(qp + (size_t)(q0) * DD, &lds[buf][c * 8])

    STAGE_Q(0, 0);
    __syncthreads();
    float lacc[2] = {0.f, 0.f};
    int cur = 0;
#pragma clang loop unroll(disable)
    for (int it = 0; it < niter; ++it) {
        if (it < niter - 1) STAGE_Q(cur ^ 1, (it + 1) * 64);
#pragma unroll
        for (int qt = 0; qt < 4; ++qt) {
            bf16x8 qa0 = *(const bf16x8*)&lds[cur][(qt * 2 + 0) * 512 + lane * 8];
            bf16x8 qa1 = *(const bf16x8*)&lds[cur][(qt * 2 + 1) * 512 + lane * 8];
#pragma unroll
            for (int t = 0; t < 2; t++) {
                f32x4 ss = (f32x4){0.f, 0.f, 0.f, 0.f};
                ss = MFMA16(qa0, kf[t][0], ss);
                ss = MFMA16(qa1, kf[t][1], ss);
                lacc[t] += EX2(ss[0]) + EX2(ss[1]) + EX2(ss[2]) + EX2(ss[3]);
            }
        }
        __syncthreads();
        cur ^= 1;
    }
#undef STAGE_Q
#pragma unroll
    for (int t = 0; t < 2; t++) {
        float v = lacc[t];
        v += __shfl_xor(v, 16);
        v += __shfl_xor(v, 32);
        if (lane < 16)
            lsum[(size_t)qs * BHX * NN + (size_t)bh * NN + kw0 + t * 16 + lane] = v;
    }
}

// ---------------- V transpose + fold 1/(l0+l1), k-PERMUTED ---------------- (r14/r15-proven combine)
__global__ __launch_bounds__(256) void k_vtrans(const u16* __restrict__ vh, const float* __restrict__ lsum,
                                                u16* __restrict__ vt) {
    __shared__ u16 lds[64 * 80];
    const int bh = blockIdx.x, n0 = blockIdx.y * 64;
    const int tid = threadIdx.x;
    const u16* src = vh + (size_t)bh * NN * DD + (size_t)n0 * DD;
    const float* l0 = lsum + (size_t)bh * NN + n0;
    const float* l1 = lsum + (size_t)BHX * NN + (size_t)bh * NN + n0;
#pragma unroll
    for (int i = 0; i < 2; i++) {
        int c = i * 256 + tid;
        int row = c >> 3, dc = c & 7;
        uint4 vraw = *(const uint4*)(src + row * DD + dc * 8);
        float rk = 1.0f / (l0[row] + l1[row]);
        u32 uu[4] = {vraw.x, vraw.y, vraw.z, vraw.w};
#pragma unroll
        for (int j = 0; j < 4; j++) {
            u16 e0 = (u16)(uu[j] & 0xffff), e1 = (u16)(uu[j] >> 16);
            lds[(dc * 8 + 2 * j) * 80 + row] = f2bf(rk * bf2f(e0));
            lds[(dc * 8 + 2 * j + 1) * 80 + row] = f2bf(rk * bf2f(e1));
        }
    }
    __syncthreads();
    u16* dst = vt + (size_t)bh * DD * NN + n0;
#pragma unroll
    for (int i = 0; i < 2; i++) {
        int c = i * 256 + tid;
        int d = c >> 3, nc = c & 7;
        int w0 = nc * 8;
        uint2 a = *(const uint2*)&lds[d * 80 + w0];
        uint2 b = *(const uint2*)&lds[d * 80 + w0 + 4];
        int hi32 = (w0 >> 5) * 32;
        int wa = w0 & 31, wb = (w0 + 4) & 31;
        int ca = ((wa & 15) >> 2) * 8 + (wa >> 4) * 4;
        int cb = ((wb & 15) >> 2) * 8 + (wb >> 4) * 4;
        *(uint2*)(dst + (size_t)d * NN + hi32 + ca) = a;
        *(uint2*)(dst + (size_t)d * NN + hi32 + cb) = b;
    }
}

// ---------------- output pass: 8 waves x 16q, grid 768, pack_rn ---------------- (round-13 proven)
__global__ __launch_bounds__(512) void k_attn(const u16* __restrict__ qh, const u16* __restrict__ kh,
                                              const u16* __restrict__ vt, float* __restrict__ out) {
    __shared__ u16 lds[2][8192];  // per buf: K 8 regions x 512 | V 8 regions x 512
    const int lin = blockIdx.x;
    const int nb = (lin & 7) * 96 + (lin >> 3); // bijective XCD swizzle
    const int bh = nb >> 4, qb = nb & 15;
    const int tid = threadIdx.x, lane = tid & 63, w = tid >> 6;  // w in [0,8)
    const int lr = lane & 15, lg = lane >> 4;
    const int qw0 = qb * 128 + w * 16;  // 16 q-rows per wave
    const u16* Q = qh + (size_t)bh * NN * DD;
    const u16* K = kh + (size_t)bh * NN * DD;
    const u16* V = vt + (size_t)bh * DD * NN;

    bf16x8 qf[2];
#pragma unroll
    for (int kk = 0; kk < 2; kk++)
        qf[kk] = *(const bf16x8*)(Q + (size_t)(qw0 + lr) * DD + kk * 32 + lg * 8);

    const int c = tid;
    const int f = c >> 6;
    const int rk = (f >> 2) * 32 + ((f >> 1) & 1) * 16 + (c & 15);
    const int doff = (f & 1) * 32 + ((c >> 4) & 3) * 8;
    const u16* kp = K + (size_t)rk * DD + doff;
    const int drow = (f & 3) * 16 + (c & 15);
    const int koff = (f >> 2) * 32 + ((c >> 4) & 3) * 8;
    const u16* vp = V + (size_t)drow * NN + koff;

#define STAGE_KV(buf, k0)                                          \
    do {                                                           \
        gload_lds16(kp + (size_t)(k0) * DD, &lds[buf][c * 8]);     \
        gload_lds16(vp + (size_t)(k0), &lds[buf][4096 + c * 8]);   \
    } while (0)

    f32x4 acc[4];
#pragma unroll
    for (int di = 0; di < 4; di++) acc[di] = (f32x4){0.f, 0.f, 0.f, 0.f};

    STAGE_KV(0, 0);
    __syncthreads();
    int cur = 0;
    for (int it = 0; it < 32; ++it) {
        if (it < 31) STAGE_KV(cur ^ 1, (it + 1) * 64);
        const u16* Lk = &lds[cur][0];
        const u16* Lv = &lds[cur][4096];
#pragma unroll
        for (int kc = 0; kc < 2; ++kc) {
            bf16x8 kf2[2][2];
#pragma unroll
            for (int t = 0; t < 2; t++)
#pragma unroll
                for (int kk = 0; kk < 2; kk++)
                    kf2[t][kk] = *(const bf16x8*)&Lk[((kc * 2 + t) * 2 + kk) * 512 + lane * 8];
            bf16x8 vf[4];
#pragma unroll
            for (int di = 0; di < 4; di++)
                vf[di] = *(const bf16x8*)&Lv[(kc * 4 + di) * 512 + lane * 8];
            f32x4 s0 = (f32x4){0.f, 0.f, 0.f, 0.f}, s1 = (f32x4){0.f, 0.f, 0.f, 0.f};
            s0 = MFMA16(kf2[0][0], qf[0], s0);
            s0 = MFMA16(kf2[0][1], qf[1], s0);
            s1 = MFMA16(kf2[1][0], qf[0], s1);
            s1 = MFMA16(kf2[1][1], qf[1], s1);
            uint4 pu;
            pu.x = pack_rn(EX2(s0[0]), EX2(s0[1]));
            pu.y = pack_rn(EX2(s0[2]), EX2(s0[3]));
            pu.z = pack_rn(EX2(s1[0]), EX2(s1[1]));
            pu.w = pack_rn(EX2(s1[2]), EX2(s1[3]));
            bf16x8 pa = __builtin_bit_cast(bf16x8, pu);
#pragma unroll
            for (int di = 0; di < 4; di++) acc[di] = MFMA16(pa, vf[di], acc[di]);
        }
        __syncthreads();
        cur ^= 1;
    }
#undef STAGE_KV

    const int b = bh / HH, h = bh % HH;
#pragma unroll
    for (int di = 0; di < 4; di++)
#pragma unroll
        for (int r = 0; r < 4; r++) {
            int q = qw0 + lg * 4 + r;
            int d = di * 16 + lr;
            out[((size_t)(b * NN + q)) * EE + h * DD + d] = acc[di][r];
        }
}

extern "C" void kernel_launch(void* const* d_in, const int* in_sizes, int n_in,
                              void* d_out, int out_size, void* d_ws, size_t ws_size,
                              hipStream_t stream) {
    const float* x = (const float*)d_in[0];
    const float* Wq = (const float*)d_in[1];
    const float* bq = (const float*)d_in[2];
    const float* Wk = (const float*)d_in[3];
    const float* bk = (const float*)d_in[4];
    const float* Wv = (const float*)d_in[5];
    const float* bv = (const float*)d_in[6];
    float* out = (float*)d_out;
    char* ws = (char*)d_ws;

    size_t off = 0;
    u16* xb = (u16*)(ws + off); off += (size_t)MM * EE * 2;
    u16* wt = (u16*)(ws + off); off += (size_t)3 * EE * EE * 2;
    u16* qh = (u16*)(ws + off); off += (size_t)BHX * NN * DD * 2;
    u16* kh = (u16*)(ws + off); off += (size_t)BHX * NN * DD * 2;
    u16* vh = (u16*)(ws + off); off += (size_t)BHX * NN * DD * 2;
    u16* vt = (u16*)(ws + off); off += (size_t)BHX * NN * DD * 2;
    float* lsum = (float*)(ws + off); off += (size_t)2 * BHX * NN * 4;  // two q-half partials

    k_cvt_x<<<dim3(3072), dim3(256), 0, stream>>>(x, xb, MM * EE / 8);
    k_wt<<<dim3(12, 12, 3), dim3(256), 0, stream>>>(Wq, Wk, Wv, wt);
    k_proj<<<dim3(64, 6, 3), dim3(256), 0, stream>>>(xb, wt, bq, bk, bv, qh, kh, vh);
    k_stats<<<dim3(768), dim3(512), 0, stream>>>(qh, kh, lsum, 16);
    k_vtrans<<<dim3(48, 32), dim3(256), 0, stream>>>(vh, lsum, vt);
    k_attn<<<dim3(768), dim3(512), 0, stream>>>(qh, kh, vt, out);
}